// Round 3
// baseline (187.339 us; speedup 1.0000x reference)
//
#include <hip/hip_runtime.h>
#include <hip/hip_bf16.h>
#include <math.h>

#define VOCAB 50257
#define VPAD  50304   // 393*128
#define NSLAB 393     // n-slabs of 128 cols
#define DMODEL 128
#define BATCH 4096
#define NW 10         // 2*WINDOW
#define LOG2E 1.4426950408889634f

#define BM 256
#define BN 128
#define GRID_M (BATCH / BM)   // 16
#define NG 98                 // slab-stride groups: gy handles slabs gy, gy+98, ...
#define TOTAL_BLOCKS (GRID_M * NG)

typedef __bf16 bf16_t;
typedef __bf16 bf16x4 __attribute__((ext_vector_type(4)));
typedef __bf16 bf16x8 __attribute__((ext_vector_type(8)));
typedef float  floatx4 __attribute__((ext_vector_type(4)));

#if __has_builtin(__builtin_amdgcn_exp2f)
#define EXP2(x) __builtin_amdgcn_exp2f(x)
#else
#define EXP2(x) exp2f(x)
#endif

typedef const __attribute__((address_space(1))) void* gvp;
typedef __attribute__((address_space(3))) void* svp;

__device__ __forceinline__ float agent_load_f32(const float* p) {
    return __hip_atomic_load(p, __ATOMIC_RELAXED, __HIP_MEMORY_SCOPE_AGENT);
}

// ---------------------------------------------------------------------------
// Kernel 1 (prep):
//  blocks [0,512):   cbow = mean of 10 ctx embeddings -> bf16 (pre-scaled by
//                    log2e), center logit fp32, sumexp zero-init.
//  blocks [512,3656): W fp32 -> bf16 padded to VPAD rows.
//  block 0 thread 0 also zeroes the completion counter for k_gemm.
// ---------------------------------------------------------------------------
#define PREP_CBOW_BLOCKS 512
#define PREP_WCONV_BLOCKS 3144   // VPAD*128 / (256*8)

__global__ void k_prep(const int* __restrict__ ctx, const int* __restrict__ center,
                       const float* __restrict__ emb, const float* __restrict__ W,
                       bf16_t* __restrict__ cbow_bf, bf16_t* __restrict__ Wb,
                       float* __restrict__ center_logit, float* __restrict__ sumexp,
                       int* __restrict__ counter) {
    const int tid = threadIdx.x;
    if (blockIdx.x < PREP_CBOW_BLOCKS) {
        if (blockIdx.x == 0 && tid == 0) *counter = 0;
        // ---- CBOW: 32 lanes per batch row, 8 rows per block ----
        const int g32 = tid >> 5;
        const int l32 = tid & 31;
        const int b = blockIdx.x * 8 + g32;
        const int* cr = ctx + b * NW;
        float4 s = make_float4(0.f, 0.f, 0.f, 0.f);
#pragma unroll
        for (int w = 0; w < NW; ++w) {
            const int id = cr[w];
            float4 v = *reinterpret_cast<const float4*>(emb + (long)id * DMODEL + l32 * 4);
            s.x += v.x; s.y += v.y; s.z += v.z; s.w += v.w;
        }
        s.x *= 0.1f; s.y *= 0.1f; s.z *= 0.1f; s.w *= 0.1f;
        bf16x4 o;
        o[0] = (bf16_t)(s.x * LOG2E); o[1] = (bf16_t)(s.y * LOG2E);
        o[2] = (bf16_t)(s.z * LOG2E); o[3] = (bf16_t)(s.w * LOG2E);
        *reinterpret_cast<bf16x4*>(cbow_bf + b * DMODEL + l32 * 4) = o;

        const int cid = center[b];
        float4 wv = *reinterpret_cast<const float4*>(W + (long)cid * DMODEL + l32 * 4);
        float p = s.x * wv.x + s.y * wv.y + s.z * wv.z + s.w * wv.w;
#pragma unroll
        for (int off = 16; off >= 1; off >>= 1) p += __shfl_xor(p, off, 64);
        if (l32 == 0) {
            center_logit[b] = p;
            sumexp[b] = 0.f;
        }
    } else {
        // ---- W convert ----
        const long base = ((long)(blockIdx.x - PREP_CBOW_BLOCKS) * 256 + tid) * 8;
        bf16x8 o;
        if (base < (long)VOCAB * DMODEL) {
            float4 a = *reinterpret_cast<const float4*>(W + base);
            float4 b = *reinterpret_cast<const float4*>(W + base + 4);
            o[0] = (bf16_t)a.x; o[1] = (bf16_t)a.y; o[2] = (bf16_t)a.z; o[3] = (bf16_t)a.w;
            o[4] = (bf16_t)b.x; o[5] = (bf16_t)b.y; o[6] = (bf16_t)b.z; o[7] = (bf16_t)b.w;
        } else {
            o = (bf16x8)(bf16_t)0.f;
        }
        *reinterpret_cast<bf16x8*>(Wb + base) = o;
    }
}

// ---------------------------------------------------------------------------
// Kernel 2: fused logits GEMM + 2^x + per-row sumexp + (last block) loss.
//   Block tile BM=256 x BN=128, K=128, 4 waves. Each block loops over n-slabs
//   s = gy, gy+NG, ... with double-buffered fragment-order LDS staging via
//   global_load_lds(16B): region f = nf*4+ks at Bs[buf] + f*512 + lane*8,
//   so compute ds_read_b128 is base+lane*16 (zero conflicts). Prefetch for
//   slab i+1 issues before compute of slab i -> the vmcnt(0) barrier drain
//   overlaps the whole compute phase. exp accumulates into per-lane partials;
//   one shuffle-reduce + atomic set per block. Last-finishing block computes
//   the final loss (device-scope counter + agent-scope loads).
// ---------------------------------------------------------------------------
__launch_bounds__(256, 2)
__global__ void k_gemm(const bf16_t* __restrict__ A, const bf16_t* __restrict__ Wb,
                       float* __restrict__ sumexp,
                       const float* __restrict__ center_logit,
                       int* __restrict__ counter, float* __restrict__ out) {
    __shared__ bf16_t Bs[2][32 * 512];   // 2 x 32 KiB = 64 KiB
    const int tid  = threadIdx.x;
    const int lane = tid & 63;
    const int wv   = tid >> 6;     // 0..3
    const int l15  = lane & 15;
    const int q    = lane >> 4;    // 0..3
    const int m0   = blockIdx.x * BM;
    const int gy   = blockIdx.y;

    // ---- Prologue: stage first slab, preload A fragments ----
    int s = gy;
    {
#pragma unroll
        for (int i = 0; i < 8; ++i) {
            const int f = wv * 8 + i;
            const int nf = f >> 2, ks = f & 3;
            const bf16_t* g = Wb + (long)(s * BN + nf * 16 + l15) * DMODEL + ks * 32 + q * 8;
            __builtin_amdgcn_global_load_lds((gvp)g, (svp)(&Bs[0][f * 512]), 16, 0, 0);
        }
    }
    bf16x8 afrag[4][4];
#pragma unroll
    for (int mf = 0; mf < 4; ++mf) {
        const bf16_t* ap = A + (long)(m0 + wv * 64 + mf * 16 + l15) * DMODEL + q * 8;
#pragma unroll
        for (int ks = 0; ks < 4; ++ks)
            afrag[mf][ks] = *reinterpret_cast<const bf16x8*>(ap + ks * 32);
    }

    float ps[4][4];   // per-lane sumexp partials [mf][reg]
#pragma unroll
    for (int mf = 0; mf < 4; ++mf)
#pragma unroll
        for (int j = 0; j < 4; ++j) ps[mf][j] = 0.f;

    __syncthreads();   // drains prologue staging
    int cur = 0;

    const floatx4 z = (floatx4){0.f, 0.f, 0.f, 0.f};
    while (true) {
        const int snext = s + NG;
        const bool has_next = (snext < NSLAB);
        if (has_next) {
            const int nb = cur ^ 1;
#pragma unroll
            for (int i = 0; i < 8; ++i) {
                const int f = wv * 8 + i;
                const int nf = f >> 2, ks = f & 3;
                const bf16_t* g = Wb + (long)(snext * BN + nf * 16 + l15) * DMODEL + ks * 32 + q * 8;
                __builtin_amdgcn_global_load_lds((gvp)g, (svp)(&Bs[nb][f * 512]), 16, 0, 0);
            }
        }

        const bool full = (s != NSLAB - 1);   // only the last slab is partial
        const bf16_t* base = &Bs[cur][0];
#pragma unroll
        for (int nf = 0; nf < 8; ++nf) {
            bf16x8 b0 = *reinterpret_cast<const bf16x8*>(base + (nf * 4 + 0) * 512 + lane * 8);
            bf16x8 b1 = *reinterpret_cast<const bf16x8*>(base + (nf * 4 + 1) * 512 + lane * 8);
            bf16x8 b2 = *reinterpret_cast<const bf16x8*>(base + (nf * 4 + 2) * 512 + lane * 8);
            bf16x8 b3 = *reinterpret_cast<const bf16x8*>(base + (nf * 4 + 3) * 512 + lane * 8);
            floatx4 c0 = __builtin_amdgcn_mfma_f32_16x16x32_bf16(afrag[0][0], b0, z, 0, 0, 0);
            floatx4 c1 = __builtin_amdgcn_mfma_f32_16x16x32_bf16(afrag[1][0], b0, z, 0, 0, 0);
            floatx4 c2 = __builtin_amdgcn_mfma_f32_16x16x32_bf16(afrag[2][0], b0, z, 0, 0, 0);
            floatx4 c3 = __builtin_amdgcn_mfma_f32_16x16x32_bf16(afrag[3][0], b0, z, 0, 0, 0);
            c0 = __builtin_amdgcn_mfma_f32_16x16x32_bf16(afrag[0][1], b1, c0, 0, 0, 0);
            c1 = __builtin_amdgcn_mfma_f32_16x16x32_bf16(afrag[1][1], b1, c1, 0, 0, 0);
            c2 = __builtin_amdgcn_mfma_f32_16x16x32_bf16(afrag[2][1], b1, c2, 0, 0, 0);
            c3 = __builtin_amdgcn_mfma_f32_16x16x32_bf16(afrag[3][1], b1, c3, 0, 0, 0);
            c0 = __builtin_amdgcn_mfma_f32_16x16x32_bf16(afrag[0][2], b2, c0, 0, 0, 0);
            c1 = __builtin_amdgcn_mfma_f32_16x16x32_bf16(afrag[1][2], b2, c1, 0, 0, 0);
            c2 = __builtin_amdgcn_mfma_f32_16x16x32_bf16(afrag[2][2], b2, c2, 0, 0, 0);
            c3 = __builtin_amdgcn_mfma_f32_16x16x32_bf16(afrag[3][2], b2, c3, 0, 0, 0);
            c0 = __builtin_amdgcn_mfma_f32_16x16x32_bf16(afrag[0][3], b3, c0, 0, 0, 0);
            c1 = __builtin_amdgcn_mfma_f32_16x16x32_bf16(afrag[1][3], b3, c1, 0, 0, 0);
            c2 = __builtin_amdgcn_mfma_f32_16x16x32_bf16(afrag[2][3], b3, c2, 0, 0, 0);
            c3 = __builtin_amdgcn_mfma_f32_16x16x32_bf16(afrag[3][3], b3, c3, 0, 0, 0);

            if (full) {
#pragma unroll
                for (int j = 0; j < 4; ++j) {
                    ps[0][j] += EXP2(c0[j]);
                    ps[1][j] += EXP2(c1[j]);
                    ps[2][j] += EXP2(c2[j]);
                    ps[3][j] += EXP2(c3[j]);
                }
            } else {
                const bool ok = (s * BN + nf * 16 + l15) < VOCAB;
#pragma unroll
                for (int j = 0; j < 4; ++j) {
                    ps[0][j] += ok ? EXP2(c0[j]) : 0.f;
                    ps[1][j] += ok ? EXP2(c1[j]) : 0.f;
                    ps[2][j] += ok ? EXP2(c2[j]) : 0.f;
                    ps[3][j] += ok ? EXP2(c3[j]) : 0.f;
                }
            }
        }

        __syncthreads();   // all waves done with Bs[cur]; drains prefetch vmcnt
        if (!has_next) break;
        s = snext;
        cur ^= 1;
    }

    // ---- Once per block: reduce partials over the 16-lane column group ----
#pragma unroll
    for (int mf = 0; mf < 4; ++mf)
#pragma unroll
        for (int j = 0; j < 4; ++j) {
            float v = ps[mf][j];
            v += __shfl_xor(v, 1, 64);
            v += __shfl_xor(v, 2, 64);
            v += __shfl_xor(v, 4, 64);
            v += __shfl_xor(v, 8, 64);
            if (l15 == 0)
                atomicAdd(&sumexp[m0 + wv * 64 + mf * 16 + q * 4 + j], v);
        }

    // ---- Completion counter: last block computes the loss ----
    int* flag = (int*)&Bs[0][0];
    float* red = (float*)&Bs[0][64];
    if (tid == 0) {
        int old = __hip_atomic_fetch_add(counter, 1, __ATOMIC_ACQ_REL,
                                         __HIP_MEMORY_SCOPE_AGENT);
        *flag = (old == TOTAL_BLOCKS - 1) ? 1 : 0;
    }
    __syncthreads();
    if (*flag) {
        float acc = 0.f;
#pragma unroll
        for (int it = 0; it < BATCH / 256; ++it) {
            const int b = it * 256 + tid;
            acc += __logf(agent_load_f32(&sumexp[b])) - center_logit[b];
        }
#pragma unroll
        for (int off = 32; off >= 1; off >>= 1) acc += __shfl_xor(acc, off, 64);
        if ((tid & 63) == 0) red[tid >> 6] = acc;
        __syncthreads();
        if (tid == 0)
            out[0] = (red[0] + red[1] + red[2] + red[3]) * (1.0f / BATCH);
    }
}

// ---------------------------------------------------------------------------
extern "C" void kernel_launch(void* const* d_in, const int* in_sizes, int n_in,
                              void* d_out, int out_size, void* d_ws, size_t ws_size,
                              hipStream_t stream) {
    const int*   ctx    = (const int*)d_in[0];
    const int*   center = (const int*)d_in[1];
    const float* emb    = (const float*)d_in[2];
    const float* W      = (const float*)d_in[3];
    float*       out    = (float*)d_out;

    char* ws = (char*)d_ws;
    // layout: Wb (12,877,824 B) | cbow (1,048,576 B) | center_logit (16,384 B)
    //         | sumexp (16,384 B) | counter (4 B)
    bf16_t* Wb           = (bf16_t*)ws;
    bf16_t* cbow         = (bf16_t*)(ws + 12877824);
    float*  center_logit = (float*)(ws + 13926400);
    float*  sumexp       = (float*)(ws + 13942784);
    int*    counter      = (int*)(ws + 13959168);

    k_prep<<<PREP_CBOW_BLOCKS + PREP_WCONV_BLOCKS, 256, 0, stream>>>(
        ctx, center, emb, W, cbow, Wb, center_logit, sumexp, counter);
    dim3 g2(GRID_M, NG);
    k_gemm<<<g2, 256, 0, stream>>>(cbow, Wb, sumexp, center_logit, counter, out);
}